// Round 17
// baseline (1088.267 us; speedup 1.0000x reference)
//
#include <hip/hip_runtime.h>
#include <math.h>

#define NITER 15
#define TPB 512
#define NBATCH 4096
#define NBPB 16
#define PI_F 3.14159265358979323846f

typedef __attribute__((ext_vector_type(8))) short short8;
typedef __attribute__((ext_vector_type(4))) float f32x4;
typedef __attribute__((ext_vector_type(4))) unsigned short ushort4v;

// ---------------- LDS layout (bytes) ----------------
// Row strides chosen ≡ 5 dwords (mod 32): 148 B (2-plane vecs), 276 B (K=128 bufs)
// -> bank start 5b+4q, max 2-way aliasing (free) vs old 144/272 (≡4 -> 8-way).
// LN/PR: 192 rows x 148 = 28416 each ; D0: 96 rows x 276 = 26496 (aliases LN)
// W0: 192 rows x 276 = 52992
#define LDS_D0   0
#define LDS_LN   0
#define LDS_PR   28416
#define LDS_W0   56832
#define LDS_WACC 109824
#define LDS_ACCN 110464
#define LDS_SLOT 110592
#define SLOT_STRIDE 25
#define LDS_TOTAL (110592 + 512*SLOT_STRIDE*4)   // 161792 <= 163840

// ---------------- ws layout ----------------
#define WS_FRAG_OFF 17920

__device__ __forceinline__ unsigned short bf16_rne(float x) {
    unsigned u = __float_as_uint(x);
    unsigned r = (u + 0x7FFFu + ((u >> 16) & 1u)) >> 16;
    return (unsigned short)r;
}
__device__ __forceinline__ float bf16_f32(unsigned short h) {
    return __uint_as_float(((unsigned)h) << 16);
}

// ===================== K1: pack MA/MTA (blocks 0..383) + build Qd (blocks 384..401) ==
__global__ void pack_and_build(const float* __restrict__ P, const float* __restrict__ Pd,
                               const float* __restrict__ Pdd, float* __restrict__ QdG,
                               unsigned short* __restrict__ MA, unsigned short* __restrict__ MTA) {
    if (blockIdx.x < 384) {
        int tid = blockIdx.x*256 + threadIdx.x;
        if (tid < 49152) {                       // MA [m][rt8][ks2][pl2][lane][8] ; A = M[r][k]
            int j = tid & 7, lane = (tid>>3)&63, pl = (tid>>9)&1, ks = (tid>>10)&1, rt = (tid>>11)&7, m = tid>>14;
            const float* src = (m==0) ? Pd : ((m==1) ? Pdd : P);
            int r = rt*16 + (lane&15);
            int k = ks*32 + (lane>>4)*8 + j;
            float x = src[r*64+k];
            unsigned short hi = bf16_rne(x);
            MA[tid] = pl ? bf16_rne(x - bf16_f32(hi)) : hi;
        } else {                                 // MTA [m][kt4][ks4][pl2][lane][8] ; A = M^T[k][r]
            int t2 = tid - 49152;
            int j = t2 & 7, lane = (t2>>3)&63, pl = (t2>>9)&1, ks = (t2>>10)&3, kt = (t2>>12)&3, m = t2>>14;
            const float* src = (m==0) ? Pd : ((m==1) ? Pdd : P);
            int k = kt*16 + (lane&15);
            int r = ks*32 + (lane>>4)*8 + j;
            float x = src[r*64+k];
            unsigned short hi = bf16_rne(x);
            MTA[t2] = pl ? bf16_rne(x - bf16_f32(hi)) : hi;
        }
    } else {
        int idx = (blockIdx.x - 384)*256 + threadIdx.x;
        if (idx < 4096) {
            int i = idx >> 6, j = idx & 63;
            float acc = 0.f;
            for (int r = 0; r < 128; ++r) {
                acc += Pd[r*64+i]*Pd[r*64+j];
                acc += Pdd[r*64+i]*Pdd[r*64+j];
                acc += P[r*64+i]*P[r*64+j];
            }
            QdG[idx] = (i == j ? 1.f : 0.f) + 2.f*acc;
        } else if (idx < 4416) {
            int r2 = idx - 4096;
            int e = r2 >> 6, k = r2 & 63;
            float v = (e == 0) ? P[k] : (e == 1) ? Pd[k] : (e == 2) ? Pdd[k]
                    : (e == 3) ? Pd[127*64+k] : Pdd[127*64+k];
            QdG[idx] = v;
        }
    }
}

// ===================== K2: invert Qd — 256-thread float4 elimination (R16, green) ==
__global__ void invert_qd(const float* __restrict__ QdG, float* __restrict__ Winv,
                          unsigned short* __restrict__ WVA) {
    __shared__ float aug[69][144];
    __shared__ float prow[144];
    __shared__ float srow[144];
    const int t = threadIdx.x;  // 256
    const int lane = t & 63;

    for (int idx = t; idx < 69*144; idx += 256) ((float*)aug)[idx] = 0.f;
    __syncthreads();
    for (int idx = t; idx < 4096; idx += 256) aug[idx >> 6][idx & 63] = QdG[idx];
    for (int idx = t; idx < 320; idx += 256) {
        int e = idx >> 6, k = idx & 63;
        float v = QdG[4096 + idx];
        aug[k][64+e] = v;
        aug[64+e][k] = v;
    }
    for (int i = t; i < 69; i += 256) aug[i][69+i] = 1.f;
    __syncthreads();

    const int tr = t >> 2;
    const int tc = t & 3;
    for (int p = 0; p < 69; ++p) {
        float bv = -1.f; int bi = p;
        for (int r = p + lane; r < 69; r += 64) {
            float a = fabsf(aug[r][p]);
            if (a > bv) { bv = a; bi = r; }
        }
        #pragma unroll
        for (int off = 32; off > 0; off >>= 1) {
            float ov = __shfl_xor(bv, off, 64);
            int   oi = __shfl_xor(bi, off, 64);
            if (ov > bv || (ov == bv && oi < bi)) { bv = ov; bi = oi; }
        }
        const int pv = bi;
        const float inv = 1.f / aug[pv][p];
        const float fi0 = aug[tr][p];
        const float fi1 = (tr + 64 < 69) ? aug[tr + 64][p] : 0.f;
        if (t < 144) {
            prow[t] = aug[pv][t] * inv;
            srow[t] = aug[p][t];
        }
        __syncthreads();
        const int cb = tc * 36;
        #pragma unroll
        for (int h = 0; h < 2; ++h) {
            const int row = tr + h*64;
            const float fi = h ? fi1 : fi0;
            if (row < 69) {
                if (row == p) {
                    #pragma unroll
                    for (int j4 = 0; j4 < 9; ++j4)
                        *(float4*)(&aug[p][cb + j4*4]) = *(const float4*)(&prow[cb + j4*4]);
                } else if (row == pv) {
                    const float f2 = srow[p];
                    #pragma unroll
                    for (int j4 = 0; j4 < 9; ++j4) {
                        float4 pvv = *(const float4*)(&prow[cb + j4*4]);
                        float4 sv  = *(const float4*)(&srow[cb + j4*4]);
                        sv.x -= f2*pvv.x; sv.y -= f2*pvv.y;
                        sv.z -= f2*pvv.z; sv.w -= f2*pvv.w;
                        *(float4*)(&aug[pv][cb + j4*4]) = sv;
                    }
                } else {
                    #pragma unroll
                    for (int j4 = 0; j4 < 9; ++j4) {
                        float4 pvv = *(const float4*)(&prow[cb + j4*4]);
                        float4 av = *(float4*)(&aug[row][cb + j4*4]);
                        av.x -= fi*pvv.x; av.y -= fi*pvv.y;
                        av.z -= fi*pvv.z; av.w -= fi*pvv.w;
                        *(float4*)(&aug[row][cb + j4*4]) = av;
                    }
                }
            }
        }
        __syncthreads();
    }

    for (int idx = t; idx < 320; idx += 256)
        Winv[4096 + idx] = aug[64 + (idx >> 6)][69 + (idx & 63)];
    for (int idx = t; idx < 8192; idx += 256) {
        int j = idx & 7, ln = (idx>>3)&63, pl = (idx>>9)&1, js = (idx>>10)&1, kt2 = idx>>11;
        int kp = kt2*16 + (ln&15);
        int jj = js*32 + (ln>>4)*8 + j;
        float x = aug[jj][69 + kp];
        unsigned short hi = bf16_rne(x);
        WVA[idx] = pl ? bf16_rne(x - bf16_f32(hi)) : hi;
    }
}

// ===================== main ADMM kernel — R13 structure; only LDS strides changed ==
// State residency rule (R4-R14): persistent accumulators must NOT be register-
// promoted; no unrolling of the m loops; no inline asm in this kernel. L and hS
// live in per-thread LDS slots; axp in scratch (L2-resident).
__device__ __forceinline__ f32x4 mfma16(short8 a, short8 b, f32x4 c) {
    return __builtin_amdgcn_mfma_f32_16x16x32_bf16(a, b, c, 0, 0, 0);
}

__global__ void __launch_bounds__(TPB, 2)
admm_kernel(const float* __restrict__ lamG, const float* __restrict__ cG,
            const float* __restrict__ beqG, const float* __restrict__ WinvG,
            const unsigned short* __restrict__ MA, const unsigned short* __restrict__ MTA,
            const unsigned short* __restrict__ WVA, float* __restrict__ outG) {
    extern __shared__ char sm[];
    float* waccF = (float*)(sm + LDS_WACC);   // [10][16]
    float* accN  = (float*)(sm + LDS_ACCN);   // [2][16]
    float* slotF = (float*)(sm + LDS_SLOT);   // [512][25]: L +0..11, hS +12..23

    const int t = threadIdx.x;
    const int lane = t & 63;
    const int w = t >> 6;
    const int b = lane & 15;
    const int q = lane >> 4;
    const int kt = w & 3;
    const int dhi = w >> 2;
    const int rt = w;
    const int bbase = blockIdx.x * NBPB;
    const int sb = t * SLOT_STRIDE;

    float cR[3][4];
    float pbq[3][4];
    unsigned axp[3][6][2];   // prev ax, bf16-packed; dynamic m -> scratch (L2-resident)

    for (int i = t; i < 160 + 32; i += TPB) ((float*)(sm + LDS_WACC))[i] = 0.f;
    #pragma unroll
    for (int i = 0; i < 12; ++i) slotF[sb + 12 + i] = 0.f;   // hS = 0

    #pragma unroll
    for (int du = 0; du < 3; ++du) {
        int dof = du*2 + dhi;
        #pragma unroll
        for (int reg = 0; reg < 4; ++reg) {
            int k = kt*16 + q*4 + reg;
            cR[du][reg] = cG[(size_t)(bbase+b)*384 + dof*64 + k];
            float ls = 0.f;
            #pragma unroll
            for (int m = 0; m < 3; ++m)
                ls += lamG[(size_t)(bbase+b)*1152 + m*384 + dof*64 + k];
            slotF[sb + du*4 + reg] = ls;                      // L init
            float s = 0.f;
            #pragma unroll
            for (int e = 0; e < 5; ++e)
                s += WinvG[(64+e)*64 + k] * beqG[(size_t)(bbase+b)*30 + dof*5 + e];
            pbq[du][reg] = s;
        }
    }

    #pragma unroll
    for (int du = 0; du < 3; ++du) {
        int dof = du*2 + dhi;
        ushort4v hi4, lo4;
        #pragma unroll
        for (int reg = 0; reg < 4; ++reg) {
            unsigned short h = bf16_rne(cR[du][reg]);
            hi4[reg] = h;
            lo4[reg] = bf16_rne(cR[du][reg] - bf16_f32(h));
        }
        int off = (kt*16 + q*4)*2;
        *(ushort4v*)(sm + LDS_PR + ((0*6+dof)*16 + b)*148 + off) = hi4;
        *(ushort4v*)(sm + LDS_PR + ((1*6+dof)*16 + b)*148 + off) = lo4;
    }
    __syncthreads();

    // ---- prologue (dynamic m loop — keep dynamic; register-promoted state miscompiles) ----
    for (int m = 0; m < 3; ++m) {
        const float bm = (m==0) ? 0.8f : ((m==1) ? 1.8f : PI_F);
        short8 aMh[2], aMl[2];
        #pragma unroll
        for (int ks = 0; ks < 2; ++ks) {
            aMh[ks] = *(const short8*)(MA + ((((m*8+rt)*2+ks)*2+0)*512 + lane*8));
            aMl[ks] = *(const short8*)(MA + ((((m*8+rt)*2+ks)*2+1)*512 + lane*8));
        }
        #pragma unroll
        for (int dof = 0; dof < 6; ++dof) {
            f32x4 acc = {0.f,0.f,0.f,0.f};
            #pragma unroll
            for (int ks = 0; ks < 2; ++ks) {
                short8 Bh = *(const short8*)(sm + LDS_PR + ((0*6+dof)*16 + b)*148 + (ks*32 + q*8)*2);
                short8 Bl = *(const short8*)(sm + LDS_PR + ((1*6+dof)*16 + b)*148 + (ks*32 + q*8)*2);
                acc = mfma16(aMh[ks], Bh, acc);
                acc = mfma16(aMh[ks], Bl, acc);
                acc = mfma16(aMl[ks], Bh, acc);
            }
            ushort4v wh, wl;
            unsigned short axh[4];
            #pragma unroll
            for (int reg = 0; reg < 4; ++reg) {
                float axn = acc[reg];
                float cl = fminf(bm, fmaxf(-bm, axn));
                float wv = axn + cl;
                unsigned short h = bf16_rne(wv);
                wh[reg] = h;
                wl[reg] = bf16_rne(wv - bf16_f32(h));
                axh[reg] = bf16_rne(axn);
            }
            int off = (rt*16 + q*4)*2;
            *(ushort4v*)(sm + LDS_W0 + ((0*6+dof)*16 + b)*276 + off) = wh;
            *(ushort4v*)(sm + LDS_W0 + ((1*6+dof)*16 + b)*276 + off) = wl;
            axp[m][dof][0] = ((unsigned)axh[1] << 16) | axh[0];
            axp[m][dof][1] = ((unsigned)axh[3] << 16) | axh[2];
        }
        __syncthreads();
        short8 aTh[4], aTl[4];
        #pragma unroll
        for (int ks = 0; ks < 4; ++ks) {
            aTh[ks] = *(const short8*)(MTA + (((((m*4+kt)*4+ks)*2+0)*512) + lane*8));
            aTl[ks] = *(const short8*)(MTA + (((((m*4+kt)*4+ks)*2+1)*512) + lane*8));
        }
        #pragma unroll
        for (int du = 0; du < 3; ++du) {
            int dof = du*2 + dhi;
            f32x4 accH = {0.f,0.f,0.f,0.f};
            #pragma unroll
            for (int ks = 0; ks < 4; ++ks) {
                short8 Bwh = *(const short8*)(sm + LDS_W0 + ((0*6+dof)*16 + b)*276 + (ks*32 + q*8)*2);
                short8 Bwl = *(const short8*)(sm + LDS_W0 + ((1*6+dof)*16 + b)*276 + (ks*32 + q*8)*2);
                accH = mfma16(aTh[ks], Bwh, accH);
                accH = mfma16(aTh[ks], Bwl, accH);
                accH = mfma16(aTl[ks], Bwh, accH);
            }
            #pragma unroll
            for (int reg = 0; reg < 4; ++reg)
                slotF[sb + 12 + du*4 + reg] += accH[reg];
        }
        __syncthreads();
    }

    // ==================== 15 iterations ====================
    for (int it = 0; it < NITER; ++it) {
        // ---- phase A: t = L + hS + c ----
        #pragma unroll
        for (int du = 0; du < 3; ++du) {
            int dof = du*2 + dhi;
            ushort4v hi4, lo4;
            #pragma unroll
            for (int reg = 0; reg < 4; ++reg) {
                float tv = slotF[sb + du*4 + reg] + slotF[sb + 12 + du*4 + reg] + cR[du][reg];
                unsigned short h = bf16_rne(tv);
                hi4[reg] = h;
                lo4[reg] = bf16_rne(tv - bf16_f32(h));
            }
            int off = (kt*16 + q*4)*2;
            *(ushort4v*)(sm + LDS_LN + ((0*6+dof)*16 + b)*148 + off) = hi4;
            *(ushort4v*)(sm + LDS_LN + ((1*6+dof)*16 + b)*148 + off) = lo4;
        }
        __syncthreads();

        // ---- phase B: primal ----
        {
            short8 aWh[2], aWl[2];
            #pragma unroll
            for (int js = 0; js < 2; ++js) {
                aWh[js] = *(const short8*)(WVA + (((kt*2+js)*2+0)*512 + lane*8));
                aWl[js] = *(const short8*)(WVA + (((kt*2+js)*2+1)*512 + lane*8));
            }
            float cdq = 0.f;
            #pragma unroll
            for (int du = 0; du < 3; ++du) {
                int dof = du*2 + dhi;
                f32x4 acc = {0.f,0.f,0.f,0.f};
                #pragma unroll
                for (int js = 0; js < 2; ++js) {
                    short8 Bh = *(const short8*)(sm + LDS_LN + ((0*6+dof)*16 + b)*148 + (js*32 + q*8)*2);
                    short8 Bl = *(const short8*)(sm + LDS_LN + ((1*6+dof)*16 + b)*148 + (js*32 + q*8)*2);
                    acc = mfma16(aWh[js], Bh, acc);
                    acc = mfma16(aWh[js], Bl, acc);
                    acc = mfma16(aWl[js], Bh, acc);
                }
                ushort4v hi4, lo4;
                #pragma unroll
                for (int reg = 0; reg < 4; ++reg) {
                    float pr = acc[reg] + pbq[du][reg];
                    float cd = pr - cR[du][reg];
                    cdq += cd * cd;
                    cR[du][reg] = pr;
                    unsigned short h = bf16_rne(pr);
                    hi4[reg] = h;
                    lo4[reg] = bf16_rne(pr - bf16_f32(h));
                }
                int off = (kt*16 + q*4)*2;
                *(ushort4v*)(sm + LDS_PR + ((0*6+dof)*16 + b)*148 + off) = hi4;
                *(ushort4v*)(sm + LDS_PR + ((1*6+dof)*16 + b)*148 + off) = lo4;
            }
            cdq += __shfl_xor(cdq, 16, 64);
            cdq += __shfl_xor(cdq, 32, 64);
            if (lane < 16) atomicAdd(&waccF[9*16 + b], cdq);
        }
        __syncthreads();

        // ---- reset own hS slots (same-thread, program order suffices) ----
        #pragma unroll
        for (int i = 0; i < 12; ++i) slotF[sb + 12 + i] = 0.f;

        // ---- phases C/D (dynamic m loop — keep dynamic) ----
        for (int m = 0; m < 3; ++m) {
            const float bm = (m==0) ? 0.8f : ((m==1) ? 1.8f : PI_F);
            short8 aMh[2], aMl[2];
            #pragma unroll
            for (int ks = 0; ks < 2; ++ks) {
                aMh[ks] = *(const short8*)(MA + ((((m*8+rt)*2+ks)*2+0)*512 + lane*8));
                aMl[ks] = *(const short8*)(MA + ((((m*8+rt)*2+ks)*2+1)*512 + lane*8));
            }
            float resq = 0.f, sdq = 0.f;
            #pragma unroll
            for (int dof = 0; dof < 6; ++dof) {
                f32x4 acc = {0.f,0.f,0.f,0.f};
                #pragma unroll
                for (int ks = 0; ks < 2; ++ks) {
                    short8 Bh = *(const short8*)(sm + LDS_PR + ((0*6+dof)*16 + b)*148 + (ks*32 + q*8)*2);
                    short8 Bl = *(const short8*)(sm + LDS_PR + ((1*6+dof)*16 + b)*148 + (ks*32 + q*8)*2);
                    acc = mfma16(aMh[ks], Bh, acc);
                    acc = mfma16(aMh[ks], Bl, acc);
                    acc = mfma16(aMl[ks], Bh, acc);
                }
                ushort4v dh, wh, wl;
                unsigned short axh[4];
                unsigned p0 = axp[m][dof][0], p1 = axp[m][dof][1];
                #pragma unroll
                for (int reg = 0; reg < 4; ++reg) {
                    float axn = acc[reg];
                    float axo = bf16_f32((unsigned short)((reg < 2 ? p0 >> (16*reg) : p1 >> (16*(reg-2))) & 0xFFFF));
                    float cl = fminf(bm, fmaxf(-bm, axn));
                    float d  = axn - cl;
                    float wv = axn + cl;
                    resq += d * d;
                    float d1 = fmaxf(0.f, bm - axn) - fmaxf(0.f, bm - axo);
                    float d2 = fmaxf(0.f, bm + axn) - fmaxf(0.f, bm + axo);
                    sdq += d1*d1 + d2*d2;
                    dh[reg] = bf16_rne(d);
                    unsigned short h = bf16_rne(wv);
                    wh[reg] = h;
                    wl[reg] = bf16_rne(wv - bf16_f32(h));
                    axh[reg] = bf16_rne(axn);
                }
                int off = (rt*16 + q*4)*2;
                *(ushort4v*)(sm + LDS_D0 + (dof*16 + b)*276 + off) = dh;
                *(ushort4v*)(sm + LDS_W0 + ((0*6+dof)*16 + b)*276 + off) = wh;
                *(ushort4v*)(sm + LDS_W0 + ((1*6+dof)*16 + b)*276 + off) = wl;
                axp[m][dof][0] = ((unsigned)axh[1] << 16) | axh[0];
                axp[m][dof][1] = ((unsigned)axh[3] << 16) | axh[2];
            }
            resq += __shfl_xor(resq, 16, 64); resq += __shfl_xor(resq, 32, 64);
            sdq  += __shfl_xor(sdq, 16, 64);  sdq  += __shfl_xor(sdq, 32, 64);
            if (lane < 16) {
                atomicAdd(&waccF[m*16 + b], resq);
                atomicAdd(&waccF[(3+m)*16 + b], sdq);
            }
            __syncthreads();

            short8 aTh[4], aTl[4];
            #pragma unroll
            for (int ks = 0; ks < 4; ++ks) {
                aTh[ks] = *(const short8*)(MTA + (((((m*4+kt)*4+ks)*2+0)*512) + lane*8));
                aTl[ks] = *(const short8*)(MTA + (((((m*4+kt)*4+ks)*2+1)*512) + lane*8));
            }
            float ldq = 0.f;
            #pragma unroll
            for (int du = 0; du < 3; ++du) {
                int dof = du*2 + dhi;
                f32x4 accD = {0.f,0.f,0.f,0.f};
                f32x4 accH = {0.f,0.f,0.f,0.f};
                #pragma unroll
                for (int ks = 0; ks < 4; ++ks) {
                    short8 Bdh = *(const short8*)(sm + LDS_D0 + (dof*16 + b)*276 + (ks*32 + q*8)*2);
                    short8 Bwh = *(const short8*)(sm + LDS_W0 + ((0*6+dof)*16 + b)*276 + (ks*32 + q*8)*2);
                    short8 Bwl = *(const short8*)(sm + LDS_W0 + ((1*6+dof)*16 + b)*276 + (ks*32 + q*8)*2);
                    accD = mfma16(aTh[ks], Bdh, accD);
                    accD = mfma16(aTl[ks], Bdh, accD);
                    accH = mfma16(aTh[ks], Bwh, accH);
                    accH = mfma16(aTh[ks], Bwl, accH);
                    accH = mfma16(aTl[ks], Bwh, accH);
                }
                #pragma unroll
                for (int reg = 0; reg < 4; ++reg) {
                    float delta = accD[reg];
                    slotF[sb + du*4 + reg] -= delta;           // L update (own LDS slot)
                    ldq += delta * delta;
                    slotF[sb + 12 + du*4 + reg] += accH[reg];  // hS accumulate
                }
            }
            ldq += __shfl_xor(ldq, 16, 64); ldq += __shfl_xor(ldq, 32, 64);
            if (lane < 16) atomicAdd(&waccF[(6+m)*16 + b], ldq);
            __syncthreads();
        }

        if (t < 16) {
            float rp = sqrtf(waccF[0*16+t]) + sqrtf(waccF[1*16+t]) + sqrtf(waccF[2*16+t]);
            float fp = sqrtf(waccF[3*16+t]) + sqrtf(waccF[4*16+t]) + sqrtf(waccF[5*16+t])
                     + sqrtf(waccF[6*16+t]) + sqrtf(waccF[7*16+t]) + sqrtf(waccF[8*16+t])
                     + sqrtf(waccF[9*16+t]);
            accN[t]      += fp;
            accN[16 + t] += rp;
            #pragma unroll
            for (int n = 0; n < 10; ++n) waccF[n*16+t] = 0.f;
        }
        __syncthreads();
    }

    #pragma unroll
    for (int du = 0; du < 3; ++du) {
        int dof = du*2 + dhi;
        #pragma unroll
        for (int reg = 0; reg < 4; ++reg) {
            int k = kt*16 + q*4 + reg;
            outG[(size_t)(bbase+b)*384 + dof*64 + k] = cR[du][reg];
        }
    }
    if (t < 16) {
        outG[(size_t)NBATCH*384 + bbase + t]          = accN[t] / 15.f;
        outG[(size_t)NBATCH*384 + NBATCH + bbase + t] = accN[16 + t] / 15.f;
    }
}

extern "C" void kernel_launch(void* const* d_in, const int* in_sizes, int n_in,
                              void* d_out, int out_size, void* d_ws, size_t ws_size,
                              hipStream_t stream) {
    const float* P     = (const float*)d_in[0];
    const float* Pdot  = (const float*)d_in[1];
    const float* Pddot = (const float*)d_in[2];
    const float* lam   = (const float*)d_in[3];
    const float* csamp = (const float*)d_in[4];
    const float* beq   = (const float*)d_in[5];
    float* out = (float*)d_out;

    float* QdG  = (float*)d_ws;            // 4416 floats; rows 64..68 become Winv rows
    float* WinvG = (float*)d_ws;           // same slot (admm reads offsets 4096..4415 only)
    unsigned short* MA  = (unsigned short*)((char*)d_ws + WS_FRAG_OFF);
    unsigned short* MTA = MA + 49152;
    unsigned short* WVA = MTA + 49152;

    hipLaunchKernelGGL(pack_and_build, dim3(402), dim3(256), 0, stream, P, Pdot, Pddot, QdG, MA, MTA);
    hipLaunchKernelGGL(invert_qd, dim3(1), dim3(256), 0, stream, QdG, WinvG, WVA);

    hipFuncSetAttribute((const void*)admm_kernel,
                        hipFuncAttributeMaxDynamicSharedMemorySize, LDS_TOTAL);
    hipLaunchKernelGGL(admm_kernel, dim3(NBATCH/NBPB), dim3(TPB), LDS_TOTAL, stream,
                       lam, csamp, beq, WinvG, MA, MTA, WVA, out);
}

// Round 19
// 429.079 us; speedup vs baseline: 2.5363x; 2.5363x over previous
//
#include <hip/hip_runtime.h>
#include <math.h>

#define NITER 15
#define TPB 512
#define NBATCH 4096
#define NBPB 16
#define PI_F 3.14159265358979323846f

typedef __attribute__((ext_vector_type(8))) short short8;
typedef __attribute__((ext_vector_type(4))) float f32x4;
typedef __attribute__((ext_vector_type(4))) unsigned short ushort4v;

// ---------------- LDS layout (bytes) ----------------
#define LDS_D0   0
#define LDS_LN   0
#define LDS_PR   27648
#define LDS_W0   55296
#define LDS_WACC 107520
#define LDS_ACCN 108160
#define LDS_SLOT 108288
#define SLOT_STRIDE 25
#define LDS_TOTAL (108288 + 512*SLOT_STRIDE*4)   // 159488 <= 163840

// ---------------- ws layout ----------------
#define WS_FRAG_OFF 17920

__device__ __forceinline__ unsigned short bf16_rne(float x) {
    unsigned u = __float_as_uint(x);
    unsigned r = (u + 0x7FFFu + ((u >> 16) & 1u)) >> 16;
    return (unsigned short)r;
}
__device__ __forceinline__ float bf16_f32(unsigned short h) {
    return __uint_as_float(((unsigned)h) << 16);
}

// ===================== K1: pack MA/MTA (blocks 0..383) + build Qd (blocks 384..401) ==
__global__ void pack_and_build(const float* __restrict__ P, const float* __restrict__ Pd,
                               const float* __restrict__ Pdd, float* __restrict__ QdG,
                               unsigned short* __restrict__ MA, unsigned short* __restrict__ MTA) {
    if (blockIdx.x < 384) {
        int tid = blockIdx.x*256 + threadIdx.x;
        if (tid < 49152) {                       // MA [m][rt8][ks2][pl2][lane][8] ; A = M[r][k]
            int j = tid & 7, lane = (tid>>3)&63, pl = (tid>>9)&1, ks = (tid>>10)&1, rt = (tid>>11)&7, m = tid>>14;
            const float* src = (m==0) ? Pd : ((m==1) ? Pdd : P);
            int r = rt*16 + (lane&15);
            int k = ks*32 + (lane>>4)*8 + j;
            float x = src[r*64+k];
            unsigned short hi = bf16_rne(x);
            MA[tid] = pl ? bf16_rne(x - bf16_f32(hi)) : hi;
        } else {                                 // MTA [m][kt4][ks4][pl2][lane][8] ; A = M^T[k][r]
            int t2 = tid - 49152;
            int j = t2 & 7, lane = (t2>>3)&63, pl = (t2>>9)&1, ks = (t2>>10)&3, kt = (t2>>12)&3, m = t2>>14;
            const float* src = (m==0) ? Pd : ((m==1) ? Pdd : P);
            int k = kt*16 + (lane&15);
            int r = ks*32 + (lane>>4)*8 + j;
            float x = src[r*64+k];
            unsigned short hi = bf16_rne(x);
            MTA[t2] = pl ? bf16_rne(x - bf16_f32(hi)) : hi;
        }
    } else {
        int idx = (blockIdx.x - 384)*256 + threadIdx.x;
        if (idx < 4096) {
            int i = idx >> 6, j = idx & 63;
            float acc = 0.f;
            for (int r = 0; r < 128; ++r) {
                acc += Pd[r*64+i]*Pd[r*64+j];
                acc += Pdd[r*64+i]*Pdd[r*64+j];
                acc += P[r*64+i]*P[r*64+j];
            }
            QdG[idx] = (i == j ? 1.f : 0.f) + 2.f*acc;
        } else if (idx < 4416) {
            int r2 = idx - 4096;
            int e = r2 >> 6, k = r2 & 63;
            float v = (e == 0) ? P[k] : (e == 1) ? Pd[k] : (e == 2) ? Pdd[k]
                    : (e == 3) ? Pd[127*64+k] : Pdd[127*64+k];
            QdG[idx] = v;
        }
    }
}

// ===================== K2: invert Qd — 256-thread float4 elimination (green) =====
__global__ void invert_qd(const float* __restrict__ QdG, float* __restrict__ Winv,
                          unsigned short* __restrict__ WVA) {
    __shared__ float aug[69][144];
    __shared__ float prow[144];
    __shared__ float srow[144];
    const int t = threadIdx.x;  // 256
    const int lane = t & 63;

    for (int idx = t; idx < 69*144; idx += 256) ((float*)aug)[idx] = 0.f;
    __syncthreads();
    for (int idx = t; idx < 4096; idx += 256) aug[idx >> 6][idx & 63] = QdG[idx];
    for (int idx = t; idx < 320; idx += 256) {
        int e = idx >> 6, k = idx & 63;
        float v = QdG[4096 + idx];
        aug[k][64+e] = v;
        aug[64+e][k] = v;
    }
    for (int i = t; i < 69; i += 256) aug[i][69+i] = 1.f;
    __syncthreads();

    const int tr = t >> 2;
    const int tc = t & 3;
    for (int p = 0; p < 69; ++p) {
        float bv = -1.f; int bi = p;
        for (int r = p + lane; r < 69; r += 64) {
            float a = fabsf(aug[r][p]);
            if (a > bv) { bv = a; bi = r; }
        }
        #pragma unroll
        for (int off = 32; off > 0; off >>= 1) {
            float ov = __shfl_xor(bv, off, 64);
            int   oi = __shfl_xor(bi, off, 64);
            if (ov > bv || (ov == bv && oi < bi)) { bv = ov; bi = oi; }
        }
        const int pv = bi;
        const float inv = 1.f / aug[pv][p];
        const float fi0 = aug[tr][p];
        const float fi1 = (tr + 64 < 69) ? aug[tr + 64][p] : 0.f;
        if (t < 144) {
            prow[t] = aug[pv][t] * inv;
            srow[t] = aug[p][t];
        }
        __syncthreads();
        const int cb = tc * 36;
        #pragma unroll
        for (int h = 0; h < 2; ++h) {
            const int row = tr + h*64;
            const float fi = h ? fi1 : fi0;
            if (row < 69) {
                if (row == p) {
                    #pragma unroll
                    for (int j4 = 0; j4 < 9; ++j4)
                        *(float4*)(&aug[p][cb + j4*4]) = *(const float4*)(&prow[cb + j4*4]);
                } else if (row == pv) {
                    const float f2 = srow[p];
                    #pragma unroll
                    for (int j4 = 0; j4 < 9; ++j4) {
                        float4 pvv = *(const float4*)(&prow[cb + j4*4]);
                        float4 sv  = *(const float4*)(&srow[cb + j4*4]);
                        sv.x -= f2*pvv.x; sv.y -= f2*pvv.y;
                        sv.z -= f2*pvv.z; sv.w -= f2*pvv.w;
                        *(float4*)(&aug[pv][cb + j4*4]) = sv;
                    }
                } else {
                    #pragma unroll
                    for (int j4 = 0; j4 < 9; ++j4) {
                        float4 pvv = *(const float4*)(&prow[cb + j4*4]);
                        float4 av = *(float4*)(&aug[row][cb + j4*4]);
                        av.x -= fi*pvv.x; av.y -= fi*pvv.y;
                        av.z -= fi*pvv.z; av.w -= fi*pvv.w;
                        *(float4*)(&aug[row][cb + j4*4]) = av;
                    }
                }
            }
        }
        __syncthreads();
    }

    for (int idx = t; idx < 320; idx += 256)
        Winv[4096 + idx] = aug[64 + (idx >> 6)][69 + (idx & 63)];
    for (int idx = t; idx < 8192; idx += 256) {
        int j = idx & 7, ln = (idx>>3)&63, pl = (idx>>9)&1, js = (idx>>10)&1, kt2 = idx>>11;
        int kp = kt2*16 + (ln&15);
        int jj = js*32 + (ln>>4)*8 + j;
        float x = aug[jj][69 + kp];
        unsigned short hi = bf16_rne(x);
        WVA[idx] = pl ? bf16_rne(x - bf16_f32(hi)) : hi;
    }
}

// ===================== main ADMM kernel — R13 VERBATIM (green, do not perturb) ==
// Hard-won constraints (R4-R18): no register-promoted persistent state; keep the
// m loops dynamic; no inline asm; LDS strides feeding b128 must be 16B multiples;
// all state-carrying bf16 conversions must be RNE (truncation bias diverges).
__device__ __forceinline__ f32x4 mfma16(short8 a, short8 b, f32x4 c) {
    return __builtin_amdgcn_mfma_f32_16x16x32_bf16(a, b, c, 0, 0, 0);
}

__global__ void __launch_bounds__(TPB, 2)
admm_kernel(const float* __restrict__ lamG, const float* __restrict__ cG,
            const float* __restrict__ beqG, const float* __restrict__ WinvG,
            const unsigned short* __restrict__ MA, const unsigned short* __restrict__ MTA,
            const unsigned short* __restrict__ WVA, float* __restrict__ outG) {
    extern __shared__ char sm[];
    float* waccF = (float*)(sm + LDS_WACC);   // [10][16]
    float* accN  = (float*)(sm + LDS_ACCN);   // [2][16]
    float* slotF = (float*)(sm + LDS_SLOT);   // [512][25]: L +0..11, hS +12..23

    const int t = threadIdx.x;
    const int lane = t & 63;
    const int w = t >> 6;
    const int b = lane & 15;
    const int q = lane >> 4;
    const int kt = w & 3;
    const int dhi = w >> 2;
    const int rt = w;
    const int bbase = blockIdx.x * NBPB;
    const int sb = t * SLOT_STRIDE;

    float cR[3][4];
    float pbq[3][4];
    unsigned axp[3][6][2];   // prev ax, bf16-packed; dynamic m -> scratch (L2-resident)

    for (int i = t; i < 160 + 32; i += TPB) ((float*)(sm + LDS_WACC))[i] = 0.f;
    #pragma unroll
    for (int i = 0; i < 12; ++i) slotF[sb + 12 + i] = 0.f;   // hS = 0

    #pragma unroll
    for (int du = 0; du < 3; ++du) {
        int dof = du*2 + dhi;
        #pragma unroll
        for (int reg = 0; reg < 4; ++reg) {
            int k = kt*16 + q*4 + reg;
            cR[du][reg] = cG[(size_t)(bbase+b)*384 + dof*64 + k];
            float ls = 0.f;
            #pragma unroll
            for (int m = 0; m < 3; ++m)
                ls += lamG[(size_t)(bbase+b)*1152 + m*384 + dof*64 + k];
            slotF[sb + du*4 + reg] = ls;                      // L init
            float s = 0.f;
            #pragma unroll
            for (int e = 0; e < 5; ++e)
                s += WinvG[(64+e)*64 + k] * beqG[(size_t)(bbase+b)*30 + dof*5 + e];
            pbq[du][reg] = s;
        }
    }

    #pragma unroll
    for (int du = 0; du < 3; ++du) {
        int dof = du*2 + dhi;
        ushort4v hi4, lo4;
        #pragma unroll
        for (int reg = 0; reg < 4; ++reg) {
            unsigned short h = bf16_rne(cR[du][reg]);
            hi4[reg] = h;
            lo4[reg] = bf16_rne(cR[du][reg] - bf16_f32(h));
        }
        int off = (kt*16 + q*4)*2;
        *(ushort4v*)(sm + LDS_PR + ((0*6+dof)*16 + b)*144 + off) = hi4;
        *(ushort4v*)(sm + LDS_PR + ((1*6+dof)*16 + b)*144 + off) = lo4;
    }
    __syncthreads();

    // ---- prologue (dynamic m loop — keep dynamic; register-promoted state miscompiles) ----
    for (int m = 0; m < 3; ++m) {
        const float bm = (m==0) ? 0.8f : ((m==1) ? 1.8f : PI_F);
        short8 aMh[2], aMl[2];
        #pragma unroll
        for (int ks = 0; ks < 2; ++ks) {
            aMh[ks] = *(const short8*)(MA + ((((m*8+rt)*2+ks)*2+0)*512 + lane*8));
            aMl[ks] = *(const short8*)(MA + ((((m*8+rt)*2+ks)*2+1)*512 + lane*8));
        }
        #pragma unroll
        for (int dof = 0; dof < 6; ++dof) {
            f32x4 acc = {0.f,0.f,0.f,0.f};
            #pragma unroll
            for (int ks = 0; ks < 2; ++ks) {
                short8 Bh = *(const short8*)(sm + LDS_PR + ((0*6+dof)*16 + b)*144 + (ks*32 + q*8)*2);
                short8 Bl = *(const short8*)(sm + LDS_PR + ((1*6+dof)*16 + b)*144 + (ks*32 + q*8)*2);
                acc = mfma16(aMh[ks], Bh, acc);
                acc = mfma16(aMh[ks], Bl, acc);
                acc = mfma16(aMl[ks], Bh, acc);
            }
            ushort4v wh, wl;
            unsigned short axh[4];
            #pragma unroll
            for (int reg = 0; reg < 4; ++reg) {
                float axn = acc[reg];
                float cl = fminf(bm, fmaxf(-bm, axn));
                float wv = axn + cl;
                unsigned short h = bf16_rne(wv);
                wh[reg] = h;
                wl[reg] = bf16_rne(wv - bf16_f32(h));
                axh[reg] = bf16_rne(axn);
            }
            int off = (rt*16 + q*4)*2;
            *(ushort4v*)(sm + LDS_W0 + ((0*6+dof)*16 + b)*272 + off) = wh;
            *(ushort4v*)(sm + LDS_W0 + ((1*6+dof)*16 + b)*272 + off) = wl;
            axp[m][dof][0] = ((unsigned)axh[1] << 16) | axh[0];
            axp[m][dof][1] = ((unsigned)axh[3] << 16) | axh[2];
        }
        __syncthreads();
        short8 aTh[4], aTl[4];
        #pragma unroll
        for (int ks = 0; ks < 4; ++ks) {
            aTh[ks] = *(const short8*)(MTA + (((((m*4+kt)*4+ks)*2+0)*512) + lane*8));
            aTl[ks] = *(const short8*)(MTA + (((((m*4+kt)*4+ks)*2+1)*512) + lane*8));
        }
        #pragma unroll
        for (int du = 0; du < 3; ++du) {
            int dof = du*2 + dhi;
            f32x4 accH = {0.f,0.f,0.f,0.f};
            #pragma unroll
            for (int ks = 0; ks < 4; ++ks) {
                short8 Bwh = *(const short8*)(sm + LDS_W0 + ((0*6+dof)*16 + b)*272 + (ks*32 + q*8)*2);
                short8 Bwl = *(const short8*)(sm + LDS_W0 + ((1*6+dof)*16 + b)*272 + (ks*32 + q*8)*2);
                accH = mfma16(aTh[ks], Bwh, accH);
                accH = mfma16(aTh[ks], Bwl, accH);
                accH = mfma16(aTl[ks], Bwh, accH);
            }
            #pragma unroll
            for (int reg = 0; reg < 4; ++reg)
                slotF[sb + 12 + du*4 + reg] += accH[reg];
        }
        __syncthreads();
    }

    // ==================== 15 iterations ====================
    for (int it = 0; it < NITER; ++it) {
        // ---- phase A: t = L + hS + c ----
        #pragma unroll
        for (int du = 0; du < 3; ++du) {
            int dof = du*2 + dhi;
            ushort4v hi4, lo4;
            #pragma unroll
            for (int reg = 0; reg < 4; ++reg) {
                float tv = slotF[sb + du*4 + reg] + slotF[sb + 12 + du*4 + reg] + cR[du][reg];
                unsigned short h = bf16_rne(tv);
                hi4[reg] = h;
                lo4[reg] = bf16_rne(tv - bf16_f32(h));
            }
            int off = (kt*16 + q*4)*2;
            *(ushort4v*)(sm + LDS_LN + ((0*6+dof)*16 + b)*144 + off) = hi4;
            *(ushort4v*)(sm + LDS_LN + ((1*6+dof)*16 + b)*144 + off) = lo4;
        }
        __syncthreads();

        // ---- phase B: primal ----
        {
            short8 aWh[2], aWl[2];
            #pragma unroll
            for (int js = 0; js < 2; ++js) {
                aWh[js] = *(const short8*)(WVA + (((kt*2+js)*2+0)*512 + lane*8));
                aWl[js] = *(const short8*)(WVA + (((kt*2+js)*2+1)*512 + lane*8));
            }
            float cdq = 0.f;
            #pragma unroll
            for (int du = 0; du < 3; ++du) {
                int dof = du*2 + dhi;
                f32x4 acc = {0.f,0.f,0.f,0.f};
                #pragma unroll
                for (int js = 0; js < 2; ++js) {
                    short8 Bh = *(const short8*)(sm + LDS_LN + ((0*6+dof)*16 + b)*144 + (js*32 + q*8)*2);
                    short8 Bl = *(const short8*)(sm + LDS_LN + ((1*6+dof)*16 + b)*144 + (js*32 + q*8)*2);
                    acc = mfma16(aWh[js], Bh, acc);
                    acc = mfma16(aWh[js], Bl, acc);
                    acc = mfma16(aWl[js], Bh, acc);
                }
                ushort4v hi4, lo4;
                #pragma unroll
                for (int reg = 0; reg < 4; ++reg) {
                    float pr = acc[reg] + pbq[du][reg];
                    float cd = pr - cR[du][reg];
                    cdq += cd * cd;
                    cR[du][reg] = pr;
                    unsigned short h = bf16_rne(pr);
                    hi4[reg] = h;
                    lo4[reg] = bf16_rne(pr - bf16_f32(h));
                }
                int off = (kt*16 + q*4)*2;
                *(ushort4v*)(sm + LDS_PR + ((0*6+dof)*16 + b)*144 + off) = hi4;
                *(ushort4v*)(sm + LDS_PR + ((1*6+dof)*16 + b)*144 + off) = lo4;
            }
            cdq += __shfl_xor(cdq, 16, 64);
            cdq += __shfl_xor(cdq, 32, 64);
            if (lane < 16) atomicAdd(&waccF[9*16 + b], cdq);
        }
        __syncthreads();

        // ---- reset own hS slots (same-thread, program order suffices) ----
        #pragma unroll
        for (int i = 0; i < 12; ++i) slotF[sb + 12 + i] = 0.f;

        // ---- phases C/D (dynamic m loop — keep dynamic) ----
        for (int m = 0; m < 3; ++m) {
            const float bm = (m==0) ? 0.8f : ((m==1) ? 1.8f : PI_F);
            short8 aMh[2], aMl[2];
            #pragma unroll
            for (int ks = 0; ks < 2; ++ks) {
                aMh[ks] = *(const short8*)(MA + ((((m*8+rt)*2+ks)*2+0)*512 + lane*8));
                aMl[ks] = *(const short8*)(MA + ((((m*8+rt)*2+ks)*2+1)*512 + lane*8));
            }
            float resq = 0.f, sdq = 0.f;
            #pragma unroll
            for (int dof = 0; dof < 6; ++dof) {
                f32x4 acc = {0.f,0.f,0.f,0.f};
                #pragma unroll
                for (int ks = 0; ks < 2; ++ks) {
                    short8 Bh = *(const short8*)(sm + LDS_PR + ((0*6+dof)*16 + b)*144 + (ks*32 + q*8)*2);
                    short8 Bl = *(const short8*)(sm + LDS_PR + ((1*6+dof)*16 + b)*144 + (ks*32 + q*8)*2);
                    acc = mfma16(aMh[ks], Bh, acc);
                    acc = mfma16(aMh[ks], Bl, acc);
                    acc = mfma16(aMl[ks], Bh, acc);
                }
                ushort4v dh, wh, wl;
                unsigned short axh[4];
                unsigned p0 = axp[m][dof][0], p1 = axp[m][dof][1];
                #pragma unroll
                for (int reg = 0; reg < 4; ++reg) {
                    float axn = acc[reg];
                    float axo = bf16_f32((unsigned short)((reg < 2 ? p0 >> (16*reg) : p1 >> (16*(reg-2))) & 0xFFFF));
                    float cl = fminf(bm, fmaxf(-bm, axn));
                    float d  = axn - cl;
                    float wv = axn + cl;
                    resq += d * d;
                    float d1 = fmaxf(0.f, bm - axn) - fmaxf(0.f, bm - axo);
                    float d2 = fmaxf(0.f, bm + axn) - fmaxf(0.f, bm + axo);
                    sdq += d1*d1 + d2*d2;
                    dh[reg] = bf16_rne(d);
                    unsigned short h = bf16_rne(wv);
                    wh[reg] = h;
                    wl[reg] = bf16_rne(wv - bf16_f32(h));
                    axh[reg] = bf16_rne(axn);
                }
                int off = (rt*16 + q*4)*2;
                *(ushort4v*)(sm + LDS_D0 + (dof*16 + b)*272 + off) = dh;
                *(ushort4v*)(sm + LDS_W0 + ((0*6+dof)*16 + b)*272 + off) = wh;
                *(ushort4v*)(sm + LDS_W0 + ((1*6+dof)*16 + b)*272 + off) = wl;
                axp[m][dof][0] = ((unsigned)axh[1] << 16) | axh[0];
                axp[m][dof][1] = ((unsigned)axh[3] << 16) | axh[2];
            }
            resq += __shfl_xor(resq, 16, 64); resq += __shfl_xor(resq, 32, 64);
            sdq  += __shfl_xor(sdq, 16, 64);  sdq  += __shfl_xor(sdq, 32, 64);
            if (lane < 16) {
                atomicAdd(&waccF[m*16 + b], resq);
                atomicAdd(&waccF[(3+m)*16 + b], sdq);
            }
            __syncthreads();

            short8 aTh[4], aTl[4];
            #pragma unroll
            for (int ks = 0; ks < 4; ++ks) {
                aTh[ks] = *(const short8*)(MTA + (((((m*4+kt)*4+ks)*2+0)*512) + lane*8));
                aTl[ks] = *(const short8*)(MTA + (((((m*4+kt)*4+ks)*2+1)*512) + lane*8));
            }
            float ldq = 0.f;
            #pragma unroll
            for (int du = 0; du < 3; ++du) {
                int dof = du*2 + dhi;
                f32x4 accD = {0.f,0.f,0.f,0.f};
                f32x4 accH = {0.f,0.f,0.f,0.f};
                #pragma unroll
                for (int ks = 0; ks < 4; ++ks) {
                    short8 Bdh = *(const short8*)(sm + LDS_D0 + (dof*16 + b)*272 + (ks*32 + q*8)*2);
                    short8 Bwh = *(const short8*)(sm + LDS_W0 + ((0*6+dof)*16 + b)*272 + (ks*32 + q*8)*2);
                    short8 Bwl = *(const short8*)(sm + LDS_W0 + ((1*6+dof)*16 + b)*272 + (ks*32 + q*8)*2);
                    accD = mfma16(aTh[ks], Bdh, accD);
                    accD = mfma16(aTl[ks], Bdh, accD);
                    accH = mfma16(aTh[ks], Bwh, accH);
                    accH = mfma16(aTh[ks], Bwl, accH);
                    accH = mfma16(aTl[ks], Bwh, accH);
                }
                #pragma unroll
                for (int reg = 0; reg < 4; ++reg) {
                    float delta = accD[reg];
                    slotF[sb + du*4 + reg] -= delta;           // L update (own LDS slot)
                    ldq += delta * delta;
                    slotF[sb + 12 + du*4 + reg] += accH[reg];  // hS accumulate
                }
            }
            ldq += __shfl_xor(ldq, 16, 64); ldq += __shfl_xor(ldq, 32, 64);
            if (lane < 16) atomicAdd(&waccF[(6+m)*16 + b], ldq);
            __syncthreads();
        }

        if (t < 16) {
            float rp = sqrtf(waccF[0*16+t]) + sqrtf(waccF[1*16+t]) + sqrtf(waccF[2*16+t]);
            float fp = sqrtf(waccF[3*16+t]) + sqrtf(waccF[4*16+t]) + sqrtf(waccF[5*16+t])
                     + sqrtf(waccF[6*16+t]) + sqrtf(waccF[7*16+t]) + sqrtf(waccF[8*16+t])
                     + sqrtf(waccF[9*16+t]);
            accN[t]      += fp;
            accN[16 + t] += rp;
            #pragma unroll
            for (int n = 0; n < 10; ++n) waccF[n*16+t] = 0.f;
        }
        __syncthreads();
    }

    #pragma unroll
    for (int du = 0; du < 3; ++du) {
        int dof = du*2 + dhi;
        #pragma unroll
        for (int reg = 0; reg < 4; ++reg) {
            int k = kt*16 + q*4 + reg;
            outG[(size_t)(bbase+b)*384 + dof*64 + k] = cR[du][reg];
        }
    }
    if (t < 16) {
        outG[(size_t)NBATCH*384 + bbase + t]          = accN[t] / 15.f;
        outG[(size_t)NBATCH*384 + NBATCH + bbase + t] = accN[16 + t] / 15.f;
    }
}

extern "C" void kernel_launch(void* const* d_in, const int* in_sizes, int n_in,
                              void* d_out, int out_size, void* d_ws, size_t ws_size,
                              hipStream_t stream) {
    const float* P     = (const float*)d_in[0];
    const float* Pdot  = (const float*)d_in[1];
    const float* Pddot = (const float*)d_in[2];
    const float* lam   = (const float*)d_in[3];
    const float* csamp = (const float*)d_in[4];
    const float* beq   = (const float*)d_in[5];
    float* out = (float*)d_out;

    float* QdG  = (float*)d_ws;            // 4416 floats; rows 64..68 become Winv rows
    float* WinvG = (float*)d_ws;           // same slot (admm reads offsets 4096..4415 only)
    unsigned short* MA  = (unsigned short*)((char*)d_ws + WS_FRAG_OFF);
    unsigned short* MTA = MA + 49152;
    unsigned short* WVA = MTA + 49152;

    hipLaunchKernelGGL(pack_and_build, dim3(402), dim3(256), 0, stream, P, Pdot, Pddot, QdG, MA, MTA);
    hipLaunchKernelGGL(invert_qd, dim3(1), dim3(256), 0, stream, QdG, WinvG, WVA);

    hipFuncSetAttribute((const void*)admm_kernel,
                        hipFuncAttributeMaxDynamicSharedMemorySize, LDS_TOTAL);
    hipLaunchKernelGGL(admm_kernel, dim3(NBATCH/NBPB), dim3(TPB), LDS_TOTAL, stream,
                       lam, csamp, beq, WinvG, MA, MTA, WVA, out);
}